// Round 3
// baseline (558.094 us; speedup 1.0000x reference)
//
#include <hip/hip_runtime.h>
#include <cstdint>
#include <cstddef>

#define NF 128
#define NH 64

// ---------------- build kernels ----------------

__global__ __launch_bounds__(256) void zero_kernel(int* __restrict__ p, int n) {
  int i = blockIdx.x * 256 + threadIdx.x;
  if (i < n) p[i] = 0;
}

__global__ __launch_bounds__(256) void count_kernel(const int* __restrict__ ei, int E,
                                                    int* __restrict__ cnt) {
  int e = blockIdx.x * 256 + threadIdx.x;
  if (e < E) atomicAdd(&cnt[ei[E + e]], 1);
}

// per-1024-element block sums
__global__ __launch_bounds__(256) void partial_kernel(const int* __restrict__ cnt, int N,
                                                      int* __restrict__ part) {
  __shared__ int sd[256];
  int t = threadIdx.x;
  int idx = blockIdx.x * 1024 + t * 4;
  int s = 0;
#pragma unroll
  for (int j = 0; j < 4; ++j)
    if (idx + j < N) s += cnt[idx + j];
  sd[t] = s;
  __syncthreads();
  for (int off = 128; off > 0; off >>= 1) {
    if (t < off) sd[t] += sd[t + off];
    __syncthreads();
  }
  if (t == 0) part[blockIdx.x] = sd[0];
}

// exclusive-scan the block partials (NB <= 128), write total to rowptr[N]
__global__ __launch_bounds__(128) void scanp_kernel(int* __restrict__ part, int NB,
                                                    int* __restrict__ rowptrN) {
  __shared__ int s[128];
  int t = threadIdx.x;
  int v = (t < NB) ? part[t] : 0;
  s[t] = v;
  __syncthreads();
  for (int off = 1; off < 128; off <<= 1) {
    int add = (t >= off) ? s[t - off] : 0;
    __syncthreads();
    s[t] += add;
    __syncthreads();
  }
  if (t < NB) part[t] = s[t] - v;  // exclusive
  if (t == 0) rowptrN[0] = s[127];
}

// rowptr (exclusive scan of cnt) + dinv = rsqrt(deg) with deg = cnt + 1 (self-loop)
__global__ __launch_bounds__(256) void rowptr_kernel(const int* __restrict__ cnt,
                                                     const int* __restrict__ part,
                                                     int* __restrict__ rowptr,
                                                     float* __restrict__ dinv, int N) {
  __shared__ int s[256];
  int t = threadIdx.x;
  int idx = blockIdx.x * 1024 + t * 4;
  int c[4];
  int ts = 0;
#pragma unroll
  for (int j = 0; j < 4; ++j) {
    c[j] = (idx + j < N) ? cnt[idx + j] : 0;
    ts += c[j];
  }
  s[t] = ts;
  __syncthreads();
  for (int off = 1; off < 256; off <<= 1) {
    int add = (t >= off) ? s[t - off] : 0;
    __syncthreads();
    s[t] += add;
    __syncthreads();
  }
  int run = s[t] - ts + part[blockIdx.x];
#pragma unroll
  for (int j = 0; j < 4; ++j) {
    if (idx + j < N) {
      rowptr[idx + j] = run;
      dinv[idx + j] = rsqrtf((float)(c[j] + 1));
    }
    run += c[j];
  }
}

// scatter edges into CSR col array, restricted to dst range [lo,hi) so the
// target col region stays L2-resident and lines assemble before writeback.
__global__ __launch_bounds__(256) void fill_kernel(const int* __restrict__ ei, int E,
                                                   const int* __restrict__ rowptr,
                                                   int* __restrict__ cnt2,
                                                   int* __restrict__ col,
                                                   int lo, int hi) {
  int e = blockIdx.x * 256 + threadIdx.x;
  if (e >= E) return;
  int d = ei[E + e];
  if (d < lo || d >= hi) return;
  int s = ei[e];
  int pos = rowptr[d] + atomicAdd(&cnt2[d], 1);
  col[pos] = s;
}

// ---------------- compute kernels ----------------

// H[n][64] = sum_k X[n][k] * W[k][64]
// Block = 64 nodes, 256 threads; K staged in 64-chunks (XsT transposed+padded).
template <int K>
__global__ __launch_bounds__(256, 4) void gemm_kernel(const float* __restrict__ X,
                                                      const float* __restrict__ W,
                                                      float* __restrict__ H, int N) {
  __shared__ float XsT[64][68];
  __shared__ float Ws[64 * 64];
  const int tid = threadIdx.x;
  const int n0 = blockIdx.x * 64;
  const int tn = (tid >> 4) * 4;  // node offset within tile
  const int tf = (tid & 15) * 4;  // feat offset

  float acc[4][4];
#pragma unroll
  for (int i = 0; i < 4; ++i)
#pragma unroll
    for (int j = 0; j < 4; ++j) acc[i][j] = 0.f;

  for (int kt = 0; kt < K / 64; ++kt) {
    {
      const float4* Wg = (const float4*)(W + (size_t)kt * 64 * 64);
      float4* Wl = (float4*)Ws;
#pragma unroll
      for (int j = 0; j < 4; ++j) Wl[tid + j * 256] = Wg[tid + j * 256];
    }
#pragma unroll
    for (int j = 0; j < 4; ++j) {
      int idx = tid + j * 256;
      int n = idx >> 4;
      int kq = idx & 15;
      float4 v = make_float4(0.f, 0.f, 0.f, 0.f);
      if (n0 + n < N)
        v = *(const float4*)(X + (size_t)(n0 + n) * K + kt * 64 + kq * 4);
      XsT[kq * 4 + 0][n] = v.x;
      XsT[kq * 4 + 1][n] = v.y;
      XsT[kq * 4 + 2][n] = v.z;
      XsT[kq * 4 + 3][n] = v.w;
    }
    __syncthreads();
#pragma unroll 8
    for (int k = 0; k < 64; ++k) {
      float4 xv = *(const float4*)(&XsT[k][tn]);
      float4 wv = *(const float4*)(&Ws[k * 64 + tf]);
      acc[0][0] = fmaf(xv.x, wv.x, acc[0][0]);
      acc[0][1] = fmaf(xv.x, wv.y, acc[0][1]);
      acc[0][2] = fmaf(xv.x, wv.z, acc[0][2]);
      acc[0][3] = fmaf(xv.x, wv.w, acc[0][3]);
      acc[1][0] = fmaf(xv.y, wv.x, acc[1][0]);
      acc[1][1] = fmaf(xv.y, wv.y, acc[1][1]);
      acc[1][2] = fmaf(xv.y, wv.z, acc[1][2]);
      acc[1][3] = fmaf(xv.y, wv.w, acc[1][3]);
      acc[2][0] = fmaf(xv.z, wv.x, acc[2][0]);
      acc[2][1] = fmaf(xv.z, wv.y, acc[2][1]);
      acc[2][2] = fmaf(xv.z, wv.z, acc[2][2]);
      acc[2][3] = fmaf(xv.z, wv.w, acc[2][3]);
      acc[3][0] = fmaf(xv.w, wv.x, acc[3][0]);
      acc[3][1] = fmaf(xv.w, wv.y, acc[3][1]);
      acc[3][2] = fmaf(xv.w, wv.z, acc[3][2]);
      acc[3][3] = fmaf(xv.w, wv.w, acc[3][3]);
    }
    __syncthreads();
  }
#pragma unroll
  for (int i = 0; i < 4; ++i) {
    int n = n0 + tn + i;
    if (n < N)
      *(float4*)(H + (size_t)n * 64 + tf) =
          make_float4(acc[i][0], acc[i][1], acc[i][2], acc[i][3]);
  }
}

// Fused: CSR aggregate (lane = feature) + bias + relu, then the NEXT layer's
// 64x64 linear applied in-register (W column per lane in VGPRs, r broadcast
// via wave-local LDS). FINAL=1: 64->2 linear + log_softmax instead.
// Each wave grid-strides over nodes to amortize the W-column register load.
template <int FINAL>
__global__ __launch_bounds__(256, 4) void prop_fused_kernel(
    const float* __restrict__ H, const int* __restrict__ rowptr,
    const int* __restrict__ col, const float* __restrict__ dinv,
    const float* __restrict__ bias, const float* __restrict__ Wn,
    const float* __restrict__ blin, float* __restrict__ out, int N) {
  __shared__ float Ws[64 * 64];
  __shared__ float rbuf[4][64];
  const int lane = threadIdx.x & 63;
  const int widx = threadIdx.x >> 6;

  float wcol[64];
  if (!FINAL) {
    for (int i = threadIdx.x; i < 64 * 64; i += 256) Ws[i] = Wn[i];
    __syncthreads();
#pragma unroll
    for (int k = 0; k < 64; ++k) wcol[k] = Ws[k * 64 + lane];
  }
  float wl0 = 0.f, wl1 = 0.f, bl0 = 0.f, bl1 = 0.f;
  if (FINAL) {
    wl0 = Wn[lane * 2 + 0];
    wl1 = Wn[lane * 2 + 1];
    bl0 = blin[0];
    bl1 = blin[1];
  }
  const float bv = bias[lane];

  const int nwaves = gridDim.x * 4;
  for (int n = blockIdx.x * 4 + widx; n < N; n += nwaves) {
    int e0 = rowptr[n];
    int e1 = rowptr[n + 1];
    float di = dinv[n];
    float acc = H[(size_t)n * 64 + lane] * (di * di);  // self-loop
    int e = e0;
    for (; e + 8 <= e1; e += 8) {
      int s[8];
      float wv[8], h[8];
#pragma unroll
      for (int j = 0; j < 8; ++j) s[j] = col[e + j];
#pragma unroll
      for (int j = 0; j < 8; ++j) wv[j] = dinv[s[j]] * di;
#pragma unroll
      for (int j = 0; j < 8; ++j) h[j] = H[(size_t)s[j] * 64 + lane];
#pragma unroll
      for (int j = 0; j < 8; ++j) acc = fmaf(wv[j], h[j], acc);
    }
    for (; e < e1; ++e) {
      int s = col[e];
      acc = fmaf(dinv[s] * di, H[(size_t)s * 64 + lane], acc);
    }
    float r = acc + bv;
    r = r > 0.f ? r : 0.f;
    if (FINAL) {
      float t0 = r * wl0;
      float t1 = r * wl1;
#pragma unroll
      for (int off = 32; off > 0; off >>= 1) {
        t0 += __shfl_xor(t0, off, 64);
        t1 += __shfl_xor(t1, off, 64);
      }
      if (lane == 0) {
        float l0 = t0 + bl0;
        float l1 = t1 + bl1;
        float m = fmaxf(l0, l1);
        float lz = m + logf(expf(l0 - m) + expf(l1 - m));
        out[(size_t)n * 2 + 0] = l0 - lz;
        out[(size_t)n * 2 + 1] = l1 - lz;
      }
    } else {
      // wave-local exchange: every lane needs all 64 r values
      rbuf[widx][lane] = r;
      asm volatile("s_waitcnt lgkmcnt(0)" ::: "memory");
      float o = 0.f;
#pragma unroll
      for (int q = 0; q < 16; ++q) {
        float4 rv = *(const float4*)(&rbuf[widx][q * 4]);
        o = fmaf(rv.x, wcol[4 * q + 0], o);
        o = fmaf(rv.y, wcol[4 * q + 1], o);
        o = fmaf(rv.z, wcol[4 * q + 2], o);
        o = fmaf(rv.w, wcol[4 * q + 3], o);
      }
      out[(size_t)n * 64 + lane] = o;
    }
  }
}

// ---------------- launcher ----------------

extern "C" void kernel_launch(void* const* d_in, const int* in_sizes, int n_in,
                              void* d_out, int out_size, void* d_ws, size_t ws_size,
                              hipStream_t stream) {
  const float* x  = (const float*)d_in[0];
  const int*   ei = (const int*)d_in[1];
  const float* W1 = (const float*)d_in[2];
  const float* b1 = (const float*)d_in[3];
  const float* W2 = (const float*)d_in[4];
  const float* b2 = (const float*)d_in[5];
  const float* W3 = (const float*)d_in[6];
  const float* b3 = (const float*)d_in[7];
  const float* Wl = (const float*)d_in[8];
  const float* bl = (const float*)d_in[9];
  float* out = (float*)d_out;

  const int N = in_sizes[0] / NF;  // 100000
  const int E = in_sizes[1] / 2;   // 1600000

  char* w = (char*)d_ws;
  size_t off = 0;
  auto alloc = [&](size_t bytes) {
    void* p = w + off;
    off += bytes;
    off = (off + 15) & ~(size_t)15;
    return p;
  };
  int*   cnt    = (int*)alloc((size_t)N * 4);
  int*   cnt2   = (int*)alloc((size_t)N * 4);
  int*   rowptr = (int*)alloc((size_t)(N + 1) * 4);
  int*   part   = (int*)alloc(256 * 4);
  float* dinv   = (float*)alloc((size_t)N * 4);
  int*   col    = (int*)alloc((size_t)E * 4);
  float* hA     = (float*)alloc((size_t)N * NH * 4);
  float* hB     = (float*)alloc((size_t)N * NH * 4);

  const int NB = (N + 1023) / 1024;  // 98 (<=128 required by scanp)

  hipLaunchKernelGGL(zero_kernel, dim3((2 * N + 255) / 256), dim3(256), 0, stream, cnt, 2 * N);
  hipLaunchKernelGGL(count_kernel, dim3((E + 255) / 256), dim3(256), 0, stream, ei, E, cnt);
  hipLaunchKernelGGL(partial_kernel, dim3(NB), dim3(256), 0, stream, cnt, N, part);
  hipLaunchKernelGGL(scanp_kernel, dim3(1), dim3(128), 0, stream, part, NB, rowptr + N);
  hipLaunchKernelGGL(rowptr_kernel, dim3(NB), dim3(256), 0, stream, cnt, part, rowptr, dinv, N);

  const int P = 8;
  const int RW = (N + P - 1) / P;  // 12500 nodes per pass
  for (int p = 0; p < P; ++p) {
    hipLaunchKernelGGL(fill_kernel, dim3((E + 255) / 256), dim3(256), 0, stream,
                       ei, E, rowptr, cnt2, col, p * RW, (p + 1) * RW);
  }

  hipLaunchKernelGGL(gemm_kernel<128>, dim3((N + 63) / 64), dim3(256), 0, stream, x, W1, hA, N);
  hipLaunchKernelGGL(prop_fused_kernel<0>, dim3(2048), dim3(256), 0, stream,
                     hA, rowptr, col, dinv, b1, W2, (const float*)nullptr, hB, N);
  hipLaunchKernelGGL(prop_fused_kernel<0>, dim3(2048), dim3(256), 0, stream,
                     hB, rowptr, col, dinv, b2, W3, (const float*)nullptr, hA, N);
  hipLaunchKernelGGL(prop_fused_kernel<1>, dim3(2048), dim3(256), 0, stream,
                     hA, rowptr, col, dinv, b3, Wl, bl, out, N);
}

// Round 4
// 492.190 us; speedup vs baseline: 1.1339x; 1.1339x over previous
//
#include <hip/hip_runtime.h>
#include <cstdint>
#include <cstddef>

#define NF 128
#define NH 64

// ---------------- build kernels ----------------

__global__ __launch_bounds__(256) void count_kernel(const int* __restrict__ ei, int E,
                                                    int* __restrict__ cnt) {
  int i = blockIdx.x * 256 + threadIdx.x;
  if (i * 4 >= E) return;
  int4 d = ((const int4*)(ei + E))[i];
  atomicAdd(&cnt[d.x], 1);
  atomicAdd(&cnt[d.y], 1);
  atomicAdd(&cnt[d.z], 1);
  atomicAdd(&cnt[d.w], 1);
}

// per-1024-element block sums
__global__ __launch_bounds__(256) void partial_kernel(const int* __restrict__ cnt, int N,
                                                      int* __restrict__ part) {
  __shared__ int sd[256];
  int t = threadIdx.x;
  int idx = blockIdx.x * 1024 + t * 4;
  int s = 0;
#pragma unroll
  for (int j = 0; j < 4; ++j)
    if (idx + j < N) s += cnt[idx + j];
  sd[t] = s;
  __syncthreads();
  for (int off = 128; off > 0; off >>= 1) {
    if (t < off) sd[t] += sd[t + off];
    __syncthreads();
  }
  if (t == 0) part[blockIdx.x] = sd[0];
}

// exclusive-scan the block partials (NB <= 128), write total to rowptr[N]
__global__ __launch_bounds__(128) void scanp_kernel(int* __restrict__ part, int NB,
                                                    int* __restrict__ rowptrN) {
  __shared__ int s[128];
  int t = threadIdx.x;
  int v = (t < NB) ? part[t] : 0;
  s[t] = v;
  __syncthreads();
  for (int off = 1; off < 128; off <<= 1) {
    int add = (t >= off) ? s[t - off] : 0;
    __syncthreads();
    s[t] += add;
    __syncthreads();
  }
  if (t < NB) part[t] = s[t] - v;  // exclusive
  if (t == 0) rowptrN[0] = s[127];
}

// rowptr (exclusive scan of cnt) + cnt2 (running cursor copy) + dinv
__global__ __launch_bounds__(256) void rowptr_kernel(const int* __restrict__ cnt,
                                                     const int* __restrict__ part,
                                                     int* __restrict__ rowptr,
                                                     int* __restrict__ cnt2,
                                                     float* __restrict__ dinv, int N) {
  __shared__ int s[256];
  int t = threadIdx.x;
  int idx = blockIdx.x * 1024 + t * 4;
  int c[4];
  int ts = 0;
#pragma unroll
  for (int j = 0; j < 4; ++j) {
    c[j] = (idx + j < N) ? cnt[idx + j] : 0;
    ts += c[j];
  }
  s[t] = ts;
  __syncthreads();
  for (int off = 1; off < 256; off <<= 1) {
    int add = (t >= off) ? s[t - off] : 0;
    __syncthreads();
    s[t] += add;
    __syncthreads();
  }
  int run = s[t] - ts + part[blockIdx.x];
#pragma unroll
  for (int j = 0; j < 4; ++j) {
    if (idx + j < N) {
      rowptr[idx + j] = run;
      cnt2[idx + j] = run;
      dinv[idx + j] = rsqrtf((float)(c[j] + 1));
    }
    run += c[j];
  }
}

// scatter edges into CSR (src, weight) pairs, restricted to dst range [lo,hi)
// so the col2 target window stays L2-resident (lines assemble before writeback).
__global__ __launch_bounds__(256) void fill_kernel(const int* __restrict__ ei, int E,
                                                   int* __restrict__ cnt2,
                                                   const float* __restrict__ dinv,
                                                   int2* __restrict__ col2,
                                                   int lo, int hi) {
  int i = blockIdx.x * 256 + threadIdx.x;
  if (i * 4 >= E) return;
  int4 sv = ((const int4*)ei)[i];
  int4 dv = ((const int4*)(ei + E))[i];
  int ss[4] = {sv.x, sv.y, sv.z, sv.w};
  int dd[4] = {dv.x, dv.y, dv.z, dv.w};
#pragma unroll
  for (int j = 0; j < 4; ++j) {
    int d = dd[j];
    if (d < lo || d >= hi) continue;
    int s = ss[j];
    float w = dinv[s] * dinv[d];
    int pos = atomicAdd(&cnt2[d], 1);
    col2[pos] = make_int2(s, __float_as_int(w));
  }
}

// ---------------- compute kernels ----------------

// H[n][64] = sum_k X[n][k] * W[k][64]
// Block = 64 nodes, 256 threads; K staged in 64-chunks (XsT transposed+padded).
template <int K>
__global__ __launch_bounds__(256, 4) void gemm_kernel(const float* __restrict__ X,
                                                      const float* __restrict__ W,
                                                      float* __restrict__ H, int N) {
  __shared__ float XsT[64][68];
  __shared__ float Ws[64 * 64];
  const int tid = threadIdx.x;
  const int n0 = blockIdx.x * 64;
  const int tn = (tid >> 4) * 4;
  const int tf = (tid & 15) * 4;

  float acc[4][4];
#pragma unroll
  for (int i = 0; i < 4; ++i)
#pragma unroll
    for (int j = 0; j < 4; ++j) acc[i][j] = 0.f;

  for (int kt = 0; kt < K / 64; ++kt) {
    {
      const float4* Wg = (const float4*)(W + (size_t)kt * 64 * 64);
      float4* Wl = (float4*)Ws;
#pragma unroll
      for (int j = 0; j < 4; ++j) Wl[tid + j * 256] = Wg[tid + j * 256];
    }
#pragma unroll
    for (int j = 0; j < 4; ++j) {
      int idx = tid + j * 256;
      int n = idx >> 4;
      int kq = idx & 15;
      float4 v = make_float4(0.f, 0.f, 0.f, 0.f);
      if (n0 + n < N)
        v = *(const float4*)(X + (size_t)(n0 + n) * K + kt * 64 + kq * 4);
      XsT[kq * 4 + 0][n] = v.x;
      XsT[kq * 4 + 1][n] = v.y;
      XsT[kq * 4 + 2][n] = v.z;
      XsT[kq * 4 + 3][n] = v.w;
    }
    __syncthreads();
#pragma unroll 8
    for (int k = 0; k < 64; ++k) {
      float4 xv = *(const float4*)(&XsT[k][tn]);
      float4 wv = *(const float4*)(&Ws[k * 64 + tf]);
      acc[0][0] = fmaf(xv.x, wv.x, acc[0][0]);
      acc[0][1] = fmaf(xv.x, wv.y, acc[0][1]);
      acc[0][2] = fmaf(xv.x, wv.z, acc[0][2]);
      acc[0][3] = fmaf(xv.x, wv.w, acc[0][3]);
      acc[1][0] = fmaf(xv.y, wv.x, acc[1][0]);
      acc[1][1] = fmaf(xv.y, wv.y, acc[1][1]);
      acc[1][2] = fmaf(xv.y, wv.z, acc[1][2]);
      acc[1][3] = fmaf(xv.y, wv.w, acc[1][3]);
      acc[2][0] = fmaf(xv.z, wv.x, acc[2][0]);
      acc[2][1] = fmaf(xv.z, wv.y, acc[2][1]);
      acc[2][2] = fmaf(xv.z, wv.z, acc[2][2]);
      acc[2][3] = fmaf(xv.z, wv.w, acc[2][3]);
      acc[3][0] = fmaf(xv.w, wv.x, acc[3][0]);
      acc[3][1] = fmaf(xv.w, wv.y, acc[3][1]);
      acc[3][2] = fmaf(xv.w, wv.z, acc[3][2]);
      acc[3][3] = fmaf(xv.w, wv.w, acc[3][3]);
    }
    __syncthreads();
  }
#pragma unroll
  for (int i = 0; i < 4; ++i) {
    int n = n0 + tn + i;
    if (n < N)
      *(float4*)(H + (size_t)n * 64 + tf) =
          make_float4(acc[i][0], acc[i][1], acc[i][2], acc[i][3]);
  }
}

// Fused: CSR aggregate (wave = node, lane = feature) + bias + relu, then the
// NEXT layer's 64x64 linear via wave-local LDS exchange (no asm barriers —
// compiler manages waits so gathers pipeline across the epilogue).
// FINAL=1: 64->2 linear + log_softmax instead.
template <int FINAL>
__global__ __launch_bounds__(256, 4) void prop_fused_kernel(
    const float* __restrict__ H, const int* __restrict__ rowptr,
    const int2* __restrict__ col2, const float* __restrict__ dinv,
    const float* __restrict__ bias, const float* __restrict__ Wn,
    const float* __restrict__ blin, float* __restrict__ out, int N) {
  __shared__ float Ws[64 * 64];
  __shared__ float rbuf[4][64];
  const int lane = threadIdx.x & 63;
  const int widx = threadIdx.x >> 6;

  if (!FINAL) {
    const float4* Wg = (const float4*)Wn;
    float4* Wl = (float4*)Ws;
    for (int i = threadIdx.x; i < 1024; i += 256) Wl[i] = Wg[i];
    __syncthreads();
  }

  int n = blockIdx.x * 4 + widx;
  n = __builtin_amdgcn_readfirstlane(n);
  if (n >= N) return;

  float wl0 = 0.f, wl1 = 0.f, bl0 = 0.f, bl1 = 0.f;
  if (FINAL) {
    wl0 = Wn[lane * 2 + 0];
    wl1 = Wn[lane * 2 + 1];
    bl0 = blin[0];
    bl1 = blin[1];
  }

  int e0 = rowptr[n];
  int e1 = rowptr[n + 1];
  float di = dinv[n];
  float acc = H[(size_t)n * 64 + lane] * (di * di);  // self-loop
  int e = e0;
  for (; e + 16 <= e1; e += 16) {
    int2 c[16];
#pragma unroll
    for (int j = 0; j < 16; ++j) c[j] = col2[e + j];
    float h[16];
#pragma unroll
    for (int j = 0; j < 16; ++j) h[j] = H[(size_t)c[j].x * 64 + lane];
#pragma unroll
    for (int j = 0; j < 16; ++j) acc = fmaf(__int_as_float(c[j].y), h[j], acc);
  }
  for (; e + 4 <= e1; e += 4) {
    int2 c[4];
#pragma unroll
    for (int j = 0; j < 4; ++j) c[j] = col2[e + j];
    float h[4];
#pragma unroll
    for (int j = 0; j < 4; ++j) h[j] = H[(size_t)c[j].x * 64 + lane];
#pragma unroll
    for (int j = 0; j < 4; ++j) acc = fmaf(__int_as_float(c[j].y), h[j], acc);
  }
  for (; e < e1; ++e) {
    int2 c = col2[e];
    acc = fmaf(__int_as_float(c.y), H[(size_t)c.x * 64 + lane], acc);
  }
  float r = acc + bias[lane];
  r = r > 0.f ? r : 0.f;

  if (FINAL) {
    float t0 = r * wl0;
    float t1 = r * wl1;
#pragma unroll
    for (int off = 32; off > 0; off >>= 1) {
      t0 += __shfl_xor(t0, off, 64);
      t1 += __shfl_xor(t1, off, 64);
    }
    if (lane == 0) {
      float l0 = t0 + bl0;
      float l1 = t1 + bl1;
      float m = fmaxf(l0, l1);
      float lz = m + logf(expf(l0 - m) + expf(l1 - m));
      out[(size_t)n * 2 + 0] = l0 - lz;
      out[(size_t)n * 2 + 1] = l1 - lz;
    }
  } else {
    rbuf[widx][lane] = r;
    __builtin_amdgcn_wave_barrier();  // ordering only; compiler inserts waits
    float o = 0.f;
#pragma unroll
    for (int q = 0; q < 16; ++q) {
      float4 rv = *(const float4*)(&rbuf[widx][4 * q]);
      o = fmaf(rv.x, Ws[(4 * q + 0) * 64 + lane], o);
      o = fmaf(rv.y, Ws[(4 * q + 1) * 64 + lane], o);
      o = fmaf(rv.z, Ws[(4 * q + 2) * 64 + lane], o);
      o = fmaf(rv.w, Ws[(4 * q + 3) * 64 + lane], o);
    }
    out[(size_t)n * 64 + lane] = o;
  }
}

// ---------------- launcher ----------------

extern "C" void kernel_launch(void* const* d_in, const int* in_sizes, int n_in,
                              void* d_out, int out_size, void* d_ws, size_t ws_size,
                              hipStream_t stream) {
  const float* x  = (const float*)d_in[0];
  const int*   ei = (const int*)d_in[1];
  const float* W1 = (const float*)d_in[2];
  const float* b1 = (const float*)d_in[3];
  const float* W2 = (const float*)d_in[4];
  const float* b2 = (const float*)d_in[5];
  const float* W3 = (const float*)d_in[6];
  const float* b3 = (const float*)d_in[7];
  const float* Wl = (const float*)d_in[8];
  const float* bl = (const float*)d_in[9];
  float* out = (float*)d_out;

  const int N = in_sizes[0] / NF;  // 100000
  const int E = in_sizes[1] / 2;   // 1600000

  char* w = (char*)d_ws;
  size_t off = 0;
  auto alloc = [&](size_t bytes) {
    void* p = w + off;
    off += bytes;
    off = (off + 15) & ~(size_t)15;
    return p;
  };
  int*   cnt    = (int*)alloc((size_t)N * 4);
  int*   cnt2   = (int*)alloc((size_t)N * 4);
  int*   rowptr = (int*)alloc((size_t)(N + 1) * 4);
  int*   part   = (int*)alloc(256 * 4);
  float* dinv   = (float*)alloc((size_t)N * 4);
  int2*  col2   = (int2*)alloc((size_t)E * 8);
  float* hA     = (float*)alloc((size_t)N * NH * 4);
  float* hB     = (float*)alloc((size_t)N * NH * 4);

  const int NB = (N + 1023) / 1024;  // 98 (<=128 required by scanp)

  hipMemsetAsync(cnt, 0, (size_t)N * 4, stream);
  hipLaunchKernelGGL(count_kernel, dim3((E / 4 + 255) / 256), dim3(256), 0, stream,
                     ei, E, cnt);
  hipLaunchKernelGGL(partial_kernel, dim3(NB), dim3(256), 0, stream, cnt, N, part);
  hipLaunchKernelGGL(scanp_kernel, dim3(1), dim3(128), 0, stream, part, NB, rowptr + N);
  hipLaunchKernelGGL(rowptr_kernel, dim3(NB), dim3(256), 0, stream,
                     cnt, part, rowptr, cnt2, dinv, N);

  const int P = 8;
  const int RW = (N + P - 1) / P;  // 12500 nodes per pass
  for (int p = 0; p < P; ++p) {
    hipLaunchKernelGGL(fill_kernel, dim3((E / 4 + 255) / 256), dim3(256), 0, stream,
                       ei, E, cnt2, dinv, col2, p * RW, (p + 1) * RW);
  }

  hipLaunchKernelGGL(gemm_kernel<128>, dim3((N + 63) / 64), dim3(256), 0, stream, x, W1, hA, N);
  hipLaunchKernelGGL(prop_fused_kernel<0>, dim3((N + 3) / 4), dim3(256), 0, stream,
                     hA, rowptr, col2, dinv, b1, W2, (const float*)nullptr, hB, N);
  hipLaunchKernelGGL(prop_fused_kernel<0>, dim3((N + 3) / 4), dim3(256), 0, stream,
                     hB, rowptr, col2, dinv, b2, W3, (const float*)nullptr, hA, N);
  hipLaunchKernelGGL(prop_fused_kernel<1>, dim3((N + 3) / 4), dim3(256), 0, stream,
                     hA, rowptr, col2, dinv, b3, Wl, bl, out, N);
}

// Round 5
// 459.812 us; speedup vs baseline: 1.2137x; 1.0704x over previous
//
#include <hip/hip_runtime.h>
#include <cstdint>
#include <cstddef>

#define NF 128
#define NH 64

// ---------------- build kernels ----------------

// dst-windowed count: pass = blockIdx%8 -> one XCD per window (L2-local atomics)
__global__ __launch_bounds__(256) void count_kernel(const int* __restrict__ ei, int E,
                                                    int* __restrict__ cnt, int RW) {
  int pass = blockIdx.x & 7;
  int i = (blockIdx.x >> 3) * 256 + threadIdx.x;
  if (i * 4 >= E) return;
  int4 d = ((const int4*)(ei + E))[i];
  int lo = pass * RW, hi = lo + RW;
  if (d.x >= lo && d.x < hi) atomicAdd(&cnt[d.x], 1);
  if (d.y >= lo && d.y < hi) atomicAdd(&cnt[d.y], 1);
  if (d.z >= lo && d.z < hi) atomicAdd(&cnt[d.z], 1);
  if (d.w >= lo && d.w < hi) atomicAdd(&cnt[d.w], 1);
}

// per-1024-element block sums
__global__ __launch_bounds__(256) void partial_kernel(const int* __restrict__ cnt, int N,
                                                      int* __restrict__ part) {
  __shared__ int sd[256];
  int t = threadIdx.x;
  int idx = blockIdx.x * 1024 + t * 4;
  int s = 0;
#pragma unroll
  for (int j = 0; j < 4; ++j)
    if (idx + j < N) s += cnt[idx + j];
  sd[t] = s;
  __syncthreads();
  for (int off = 128; off > 0; off >>= 1) {
    if (t < off) sd[t] += sd[t + off];
    __syncthreads();
  }
  if (t == 0) part[blockIdx.x] = sd[0];
}

// exclusive-scan the block partials (NB <= 128), write total to rowptr[N]
__global__ __launch_bounds__(128) void scanp_kernel(int* __restrict__ part, int NB,
                                                    int* __restrict__ rowptrN) {
  __shared__ int s[128];
  int t = threadIdx.x;
  int v = (t < NB) ? part[t] : 0;
  s[t] = v;
  __syncthreads();
  for (int off = 1; off < 128; off <<= 1) {
    int add = (t >= off) ? s[t - off] : 0;
    __syncthreads();
    s[t] += add;
    __syncthreads();
  }
  if (t < NB) part[t] = s[t] - v;  // exclusive
  if (t == 0) rowptrN[0] = s[127];
}

// rowptr (exclusive scan of cnt) + cnt2 (running cursor copy) + dinv
__global__ __launch_bounds__(256) void rowptr_kernel(const int* __restrict__ cnt,
                                                     const int* __restrict__ part,
                                                     int* __restrict__ rowptr,
                                                     int* __restrict__ cnt2,
                                                     float* __restrict__ dinv, int N) {
  __shared__ int s[256];
  int t = threadIdx.x;
  int idx = blockIdx.x * 1024 + t * 4;
  int c[4];
  int ts = 0;
#pragma unroll
  for (int j = 0; j < 4; ++j) {
    c[j] = (idx + j < N) ? cnt[idx + j] : 0;
    ts += c[j];
  }
  s[t] = ts;
  __syncthreads();
  for (int off = 1; off < 256; off <<= 1) {
    int add = (t >= off) ? s[t - off] : 0;
    __syncthreads();
    s[t] += add;
    __syncthreads();
  }
  int run = s[t] - ts + part[blockIdx.x];
#pragma unroll
  for (int j = 0; j < 4; ++j) {
    if (idx + j < N) {
      rowptr[idx + j] = run;
      cnt2[idx + j] = run;
      dinv[idx + j] = rsqrtf((float)(c[j] + 1));
    }
    run += c[j];
  }
}

// dst-windowed CSR scatter, pass = blockIdx%8 -> one XCD per col2 window so
// lines assemble in that XCD's L2 before writeback.
__global__ __launch_bounds__(256) void fill_kernel(const int* __restrict__ ei, int E,
                                                   int* __restrict__ cnt2,
                                                   const float* __restrict__ dinv,
                                                   int2* __restrict__ col2, int RW) {
  int pass = blockIdx.x & 7;
  int i = (blockIdx.x >> 3) * 256 + threadIdx.x;
  if (i * 4 >= E) return;
  int4 sv = ((const int4*)ei)[i];
  int4 dv = ((const int4*)(ei + E))[i];
  int lo = pass * RW, hi = lo + RW;
  int ss[4] = {sv.x, sv.y, sv.z, sv.w};
  int dd[4] = {dv.x, dv.y, dv.z, dv.w};
#pragma unroll
  for (int j = 0; j < 4; ++j) {
    int d = dd[j];
    if (d < lo || d >= hi) continue;
    int s = ss[j];
    float w = dinv[s] * dinv[d];
    int pos = atomicAdd(&cnt2[d], 1);
    col2[pos] = make_int2(s, __float_as_int(w));
  }
}

// ---------------- compute kernels ----------------

// H[n][64] = sum_k X[n][k] * W[k][64]
// Block = 64 nodes, 256 threads; K staged in 64-chunks (XsT transposed+padded).
template <int K>
__global__ __launch_bounds__(256, 4) void gemm_kernel(const float* __restrict__ X,
                                                      const float* __restrict__ W,
                                                      float* __restrict__ H, int N) {
  __shared__ float XsT[64][68];
  __shared__ float Ws[64 * 64];
  const int tid = threadIdx.x;
  const int n0 = blockIdx.x * 64;
  const int tn = (tid >> 4) * 4;
  const int tf = (tid & 15) * 4;

  float acc[4][4];
#pragma unroll
  for (int i = 0; i < 4; ++i)
#pragma unroll
    for (int j = 0; j < 4; ++j) acc[i][j] = 0.f;

  for (int kt = 0; kt < K / 64; ++kt) {
    {
      const float4* Wg = (const float4*)(W + (size_t)kt * 64 * 64);
      float4* Wl = (float4*)Ws;
#pragma unroll
      for (int j = 0; j < 4; ++j) Wl[tid + j * 256] = Wg[tid + j * 256];
    }
#pragma unroll
    for (int j = 0; j < 4; ++j) {
      int idx = tid + j * 256;
      int n = idx >> 4;
      int kq = idx & 15;
      float4 v = make_float4(0.f, 0.f, 0.f, 0.f);
      if (n0 + n < N)
        v = *(const float4*)(X + (size_t)(n0 + n) * K + kt * 64 + kq * 4);
      XsT[kq * 4 + 0][n] = v.x;
      XsT[kq * 4 + 1][n] = v.y;
      XsT[kq * 4 + 2][n] = v.z;
      XsT[kq * 4 + 3][n] = v.w;
    }
    __syncthreads();
#pragma unroll 8
    for (int k = 0; k < 64; ++k) {
      float4 xv = *(const float4*)(&XsT[k][tn]);
      float4 wv = *(const float4*)(&Ws[k * 64 + tf]);
      acc[0][0] = fmaf(xv.x, wv.x, acc[0][0]);
      acc[0][1] = fmaf(xv.x, wv.y, acc[0][1]);
      acc[0][2] = fmaf(xv.x, wv.z, acc[0][2]);
      acc[0][3] = fmaf(xv.x, wv.w, acc[0][3]);
      acc[1][0] = fmaf(xv.y, wv.x, acc[1][0]);
      acc[1][1] = fmaf(xv.y, wv.y, acc[1][1]);
      acc[1][2] = fmaf(xv.y, wv.z, acc[1][2]);
      acc[1][3] = fmaf(xv.y, wv.w, acc[1][3]);
      acc[2][0] = fmaf(xv.z, wv.x, acc[2][0]);
      acc[2][1] = fmaf(xv.z, wv.y, acc[2][1]);
      acc[2][2] = fmaf(xv.z, wv.z, acc[2][2]);
      acc[2][3] = fmaf(xv.z, wv.w, acc[2][3]);
      acc[3][0] = fmaf(xv.w, wv.x, acc[3][0]);
      acc[3][1] = fmaf(xv.w, wv.y, acc[3][1]);
      acc[3][2] = fmaf(xv.w, wv.z, acc[3][2]);
      acc[3][3] = fmaf(xv.w, wv.w, acc[3][3]);
    }
    __syncthreads();
  }
#pragma unroll
  for (int i = 0; i < 4; ++i) {
    int n = n0 + tn + i;
    if (n < N)
      *(float4*)(H + (size_t)n * 64 + tf) =
          make_float4(acc[i][0], acc[i][1], acc[i][2], acc[i][3]);
  }
}

// Fused: CSR aggregate (wave = node, lane = feature) + bias + relu, then the
// NEXT layer's 64x64 linear via wave-local LDS exchange.
// Gather loop is software-pipelined: 8-deep batches with the next batch's
// (src,w) prefetched during the current fma block; 2 accumulators.
template <int FINAL>
__global__ __launch_bounds__(256) void prop_fused_kernel(
    const float* __restrict__ H, const int* __restrict__ rowptr,
    const int2* __restrict__ col2, const float* __restrict__ dinv,
    const float* __restrict__ bias, const float* __restrict__ Wn,
    const float* __restrict__ blin, float* __restrict__ out, int N) {
  __shared__ float Ws[64 * 64];
  __shared__ float rbuf[4][64];
  const int lane = threadIdx.x & 63;
  const int widx = threadIdx.x >> 6;

  if (!FINAL) {
    const float4* Wg = (const float4*)Wn;
    float4* Wl = (float4*)Ws;
    for (int i = threadIdx.x; i < 1024; i += 256) Wl[i] = Wg[i];
    __syncthreads();
  }

  int n = blockIdx.x * 4 + widx;
  n = __builtin_amdgcn_readfirstlane(n);
  if (n >= N) return;

  float wl0 = 0.f, wl1 = 0.f, bl0 = 0.f, bl1 = 0.f;
  if (FINAL) {
    wl0 = Wn[lane * 2 + 0];
    wl1 = Wn[lane * 2 + 1];
    bl0 = blin[0];
    bl1 = blin[1];
  }

  int e0 = rowptr[n];
  int e1 = rowptr[n + 1];
  float di = dinv[n];
  const int2* ec = col2 + e0;
  const int m = e1 - e0;

  float acc0 = H[(size_t)n * 64 + lane] * (di * di);  // self-loop
  float acc1 = 0.f;

  int sC[8], sN[8];
  float wC[8], wN[8];
  const int nfull = m >> 3;

#define LOADC(S, W, base)                           \
  {                                                 \
    _Pragma("unroll") for (int j = 0; j < 8; ++j) { \
      int2 c = ec[(base) + j];                      \
      S[j] = c.x;                                   \
      W[j] = __int_as_float(c.y);                   \
    }                                               \
  }

  if (nfull > 0) LOADC(sC, wC, 0)
  for (int b = 0; b < nfull; ++b) {
    float h[8];
#pragma unroll
    for (int j = 0; j < 8; ++j) h[j] = H[(size_t)sC[j] * 64 + lane];
    if (b + 1 < nfull) LOADC(sN, wN, (b + 1) * 8)
#pragma unroll
    for (int j = 0; j < 8; ++j) {
      if (j & 1)
        acc1 = fmaf(wC[j], h[j], acc1);
      else
        acc0 = fmaf(wC[j], h[j], acc0);
    }
#pragma unroll
    for (int j = 0; j < 8; ++j) {
      sC[j] = sN[j];
      wC[j] = wN[j];
    }
  }
#undef LOADC
  for (int t = nfull * 8; t < m; ++t) {
    int2 c = ec[t];
    acc0 = fmaf(__int_as_float(c.y), H[(size_t)c.x * 64 + lane], acc0);
  }
  float r = acc0 + acc1 + bias[lane];
  r = r > 0.f ? r : 0.f;

  if (FINAL) {
    float t0 = r * wl0;
    float t1 = r * wl1;
#pragma unroll
    for (int off = 32; off > 0; off >>= 1) {
      t0 += __shfl_xor(t0, off, 64);
      t1 += __shfl_xor(t1, off, 64);
    }
    if (lane == 0) {
      float l0 = t0 + bl0;
      float l1 = t1 + bl1;
      float mx = fmaxf(l0, l1);
      float lz = mx + logf(expf(l0 - mx) + expf(l1 - mx));
      out[(size_t)n * 2 + 0] = l0 - lz;
      out[(size_t)n * 2 + 1] = l1 - lz;
    }
  } else {
    rbuf[widx][lane] = r;
    __builtin_amdgcn_wave_barrier();  // ordering only; compiler inserts waits
    float o = 0.f;
#pragma unroll
    for (int q = 0; q < 16; ++q) {
      float4 rv = *(const float4*)(&rbuf[widx][4 * q]);
      o = fmaf(rv.x, Ws[(4 * q + 0) * 64 + lane], o);
      o = fmaf(rv.y, Ws[(4 * q + 1) * 64 + lane], o);
      o = fmaf(rv.z, Ws[(4 * q + 2) * 64 + lane], o);
      o = fmaf(rv.w, Ws[(4 * q + 3) * 64 + lane], o);
    }
    out[(size_t)n * 64 + lane] = o;
  }
}

// ---------------- launcher ----------------

extern "C" void kernel_launch(void* const* d_in, const int* in_sizes, int n_in,
                              void* d_out, int out_size, void* d_ws, size_t ws_size,
                              hipStream_t stream) {
  const float* x  = (const float*)d_in[0];
  const int*   ei = (const int*)d_in[1];
  const float* W1 = (const float*)d_in[2];
  const float* b1 = (const float*)d_in[3];
  const float* W2 = (const float*)d_in[4];
  const float* b2 = (const float*)d_in[5];
  const float* W3 = (const float*)d_in[6];
  const float* b3 = (const float*)d_in[7];
  const float* Wl = (const float*)d_in[8];
  const float* bl = (const float*)d_in[9];
  float* out = (float*)d_out;

  const int N = in_sizes[0] / NF;  // 100000
  const int E = in_sizes[1] / 2;   // 1600000

  char* w = (char*)d_ws;
  size_t off = 0;
  auto alloc = [&](size_t bytes) {
    void* p = w + off;
    off += bytes;
    off = (off + 15) & ~(size_t)15;
    return p;
  };
  int*   cnt    = (int*)alloc((size_t)N * 4);
  int*   cnt2   = (int*)alloc((size_t)N * 4);
  int*   rowptr = (int*)alloc((size_t)(N + 1) * 4);
  int*   part   = (int*)alloc(256 * 4);
  float* dinv   = (float*)alloc((size_t)N * 4);
  int2*  col2   = (int2*)alloc((size_t)E * 8);
  float* hA     = (float*)alloc((size_t)N * NH * 4);
  float* hB     = (float*)alloc((size_t)N * NH * 4);

  const int NB = (N + 1023) / 1024;       // 98 (<=128 required by scanp)
  const int RW = (N + 7) / 8;             // 12500-node dst window per XCD
  const int NCHUNK = (E / 4 + 255) / 256; // edge-quad chunks

  hipMemsetAsync(cnt, 0, (size_t)N * 4, stream);
  hipLaunchKernelGGL(count_kernel, dim3(8 * NCHUNK), dim3(256), 0, stream,
                     ei, E, cnt, RW);
  hipLaunchKernelGGL(partial_kernel, dim3(NB), dim3(256), 0, stream, cnt, N, part);
  hipLaunchKernelGGL(scanp_kernel, dim3(1), dim3(128), 0, stream, part, NB, rowptr + N);
  hipLaunchKernelGGL(rowptr_kernel, dim3(NB), dim3(256), 0, stream,
                     cnt, part, rowptr, cnt2, dinv, N);
  hipLaunchKernelGGL(fill_kernel, dim3(8 * NCHUNK), dim3(256), 0, stream,
                     ei, E, cnt2, dinv, col2, RW);

  hipLaunchKernelGGL(gemm_kernel<128>, dim3((N + 63) / 64), dim3(256), 0, stream, x, W1, hA, N);
  hipLaunchKernelGGL(prop_fused_kernel<0>, dim3((N + 3) / 4), dim3(256), 0, stream,
                     hA, rowptr, col2, dinv, b1, W2, (const float*)nullptr, hB, N);
  hipLaunchKernelGGL(prop_fused_kernel<0>, dim3((N + 3) / 4), dim3(256), 0, stream,
                     hB, rowptr, col2, dinv, b2, W3, (const float*)nullptr, hA, N);
  hipLaunchKernelGGL(prop_fused_kernel<1>, dim3((N + 3) / 4), dim3(256), 0, stream,
                     hA, rowptr, col2, dinv, b3, Wl, bl, out, N);
}

// Round 6
// 444.944 us; speedup vs baseline: 1.2543x; 1.0334x over previous
//
#include <hip/hip_runtime.h>
#include <cstdint>
#include <cstddef>

#define NF 128
#define NH 64

typedef unsigned int uint32;

// bf16 helpers (RNE pack, cheap unpack)
__device__ inline unsigned short f2bf(float f) {
  unsigned int u = __float_as_uint(f);
  return (unsigned short)((u + 0x7FFF + ((u >> 16) & 1)) >> 16);
}
__device__ inline float bf2f_lo(uint32 u) { return __uint_as_float(u << 16); }
__device__ inline float bf2f_hi(uint32 u) { return __uint_as_float(u & 0xFFFF0000u); }

// ---------------- build kernels ----------------

// dst-windowed count: pass = blockIdx%8 -> one XCD per window (L2-local atomics)
__global__ __launch_bounds__(256) void count_kernel(const int* __restrict__ ei, int E,
                                                    int* __restrict__ cnt, int RW) {
  int pass = blockIdx.x & 7;
  int i = (blockIdx.x >> 3) * 256 + threadIdx.x;
  if (i * 4 >= E) return;
  int4 d = ((const int4*)(ei + E))[i];
  int lo = pass * RW, hi = lo + RW;
  if (d.x >= lo && d.x < hi) atomicAdd(&cnt[d.x], 1);
  if (d.y >= lo && d.y < hi) atomicAdd(&cnt[d.y], 1);
  if (d.z >= lo && d.z < hi) atomicAdd(&cnt[d.z], 1);
  if (d.w >= lo && d.w < hi) atomicAdd(&cnt[d.w], 1);
}

// per-1024-element block sums
__global__ __launch_bounds__(256) void partial_kernel(const int* __restrict__ cnt, int N,
                                                      int* __restrict__ part) {
  __shared__ int sd[256];
  int t = threadIdx.x;
  int idx = blockIdx.x * 1024 + t * 4;
  int s = 0;
#pragma unroll
  for (int j = 0; j < 4; ++j)
    if (idx + j < N) s += cnt[idx + j];
  sd[t] = s;
  __syncthreads();
  for (int off = 128; off > 0; off >>= 1) {
    if (t < off) sd[t] += sd[t + off];
    __syncthreads();
  }
  if (t == 0) part[blockIdx.x] = sd[0];
}

// exclusive-scan the block partials (NB <= 128), write total to rowptr[N]
__global__ __launch_bounds__(128) void scanp_kernel(int* __restrict__ part, int NB,
                                                    int* __restrict__ rowptrN) {
  __shared__ int s[128];
  int t = threadIdx.x;
  int v = (t < NB) ? part[t] : 0;
  s[t] = v;
  __syncthreads();
  for (int off = 1; off < 128; off <<= 1) {
    int add = (t >= off) ? s[t - off] : 0;
    __syncthreads();
    s[t] += add;
    __syncthreads();
  }
  if (t < NB) part[t] = s[t] - v;  // exclusive
  if (t == 0) rowptrN[0] = s[127];
}

// rowptr (exclusive scan of cnt) + cnt2 (running cursor copy) + dinv
__global__ __launch_bounds__(256) void rowptr_kernel(const int* __restrict__ cnt,
                                                     const int* __restrict__ part,
                                                     int* __restrict__ rowptr,
                                                     int* __restrict__ cnt2,
                                                     float* __restrict__ dinv, int N) {
  __shared__ int s[256];
  int t = threadIdx.x;
  int idx = blockIdx.x * 1024 + t * 4;
  int c[4];
  int ts = 0;
#pragma unroll
  for (int j = 0; j < 4; ++j) {
    c[j] = (idx + j < N) ? cnt[idx + j] : 0;
    ts += c[j];
  }
  s[t] = ts;
  __syncthreads();
  for (int off = 1; off < 256; off <<= 1) {
    int add = (t >= off) ? s[t - off] : 0;
    __syncthreads();
    s[t] += add;
    __syncthreads();
  }
  int run = s[t] - ts + part[blockIdx.x];
#pragma unroll
  for (int j = 0; j < 4; ++j) {
    if (idx + j < N) {
      rowptr[idx + j] = run;
      cnt2[idx + j] = run;
      dinv[idx + j] = rsqrtf((float)(c[j] + 1));
    }
    run += c[j];
  }
}

// dst-windowed CSR scatter, pass = blockIdx%8 -> one XCD per col2 window so
// lines assemble in that XCD's L2 before writeback.
__global__ __launch_bounds__(256) void fill_kernel(const int* __restrict__ ei, int E,
                                                   int* __restrict__ cnt2,
                                                   const float* __restrict__ dinv,
                                                   int2* __restrict__ col2, int RW) {
  int pass = blockIdx.x & 7;
  int i = (blockIdx.x >> 3) * 256 + threadIdx.x;
  if (i * 4 >= E) return;
  int4 sv = ((const int4*)ei)[i];
  int4 dv = ((const int4*)(ei + E))[i];
  int lo = pass * RW, hi = lo + RW;
  int ss[4] = {sv.x, sv.y, sv.z, sv.w};
  int dd[4] = {dv.x, dv.y, dv.z, dv.w};
#pragma unroll
  for (int j = 0; j < 4; ++j) {
    int d = dd[j];
    if (d < lo || d >= hi) continue;
    int s = ss[j];
    float w = dinv[s] * dinv[d];
    int pos = atomicAdd(&cnt2[d], 1);
    col2[pos] = make_int2(s, __float_as_int(w));
  }
}

// ---------------- compute kernels ----------------

// H[n][64](bf16) = sum_k X[n][k](f32) * W[k][64]
// Block = 64 nodes, 256 threads; K staged in 64-chunks (XsT transposed+padded).
template <int K>
__global__ __launch_bounds__(256, 4) void gemm_kernel(const float* __restrict__ X,
                                                      const float* __restrict__ W,
                                                      uint32* __restrict__ Hb, int N) {
  __shared__ float XsT[64][68];
  __shared__ float Ws[64 * 64];
  const int tid = threadIdx.x;
  const int n0 = blockIdx.x * 64;
  const int tn = (tid >> 4) * 4;
  const int tf = (tid & 15) * 4;

  float acc[4][4];
#pragma unroll
  for (int i = 0; i < 4; ++i)
#pragma unroll
    for (int j = 0; j < 4; ++j) acc[i][j] = 0.f;

  for (int kt = 0; kt < K / 64; ++kt) {
    {
      const float4* Wg = (const float4*)(W + (size_t)kt * 64 * 64);
      float4* Wl = (float4*)Ws;
#pragma unroll
      for (int j = 0; j < 4; ++j) Wl[tid + j * 256] = Wg[tid + j * 256];
    }
#pragma unroll
    for (int j = 0; j < 4; ++j) {
      int idx = tid + j * 256;
      int n = idx >> 4;
      int kq = idx & 15;
      float4 v = make_float4(0.f, 0.f, 0.f, 0.f);
      if (n0 + n < N)
        v = *(const float4*)(X + (size_t)(n0 + n) * K + kt * 64 + kq * 4);
      XsT[kq * 4 + 0][n] = v.x;
      XsT[kq * 4 + 1][n] = v.y;
      XsT[kq * 4 + 2][n] = v.z;
      XsT[kq * 4 + 3][n] = v.w;
    }
    __syncthreads();
#pragma unroll 8
    for (int k = 0; k < 64; ++k) {
      float4 xv = *(const float4*)(&XsT[k][tn]);
      float4 wv = *(const float4*)(&Ws[k * 64 + tf]);
      acc[0][0] = fmaf(xv.x, wv.x, acc[0][0]);
      acc[0][1] = fmaf(xv.x, wv.y, acc[0][1]);
      acc[0][2] = fmaf(xv.x, wv.z, acc[0][2]);
      acc[0][3] = fmaf(xv.x, wv.w, acc[0][3]);
      acc[1][0] = fmaf(xv.y, wv.x, acc[1][0]);
      acc[1][1] = fmaf(xv.y, wv.y, acc[1][1]);
      acc[1][2] = fmaf(xv.y, wv.z, acc[1][2]);
      acc[1][3] = fmaf(xv.y, wv.w, acc[1][3]);
      acc[2][0] = fmaf(xv.z, wv.x, acc[2][0]);
      acc[2][1] = fmaf(xv.z, wv.y, acc[2][1]);
      acc[2][2] = fmaf(xv.z, wv.z, acc[2][2]);
      acc[2][3] = fmaf(xv.z, wv.w, acc[2][3]);
      acc[3][0] = fmaf(xv.w, wv.x, acc[3][0]);
      acc[3][1] = fmaf(xv.w, wv.y, acc[3][1]);
      acc[3][2] = fmaf(xv.w, wv.z, acc[3][2]);
      acc[3][3] = fmaf(xv.w, wv.w, acc[3][3]);
    }
    __syncthreads();
  }
#pragma unroll
  for (int i = 0; i < 4; ++i) {
    int n = n0 + tn + i;
    if (n < N) {
      uint32 p0 = (uint32)f2bf(acc[i][0]) | ((uint32)f2bf(acc[i][1]) << 16);
      uint32 p1 = (uint32)f2bf(acc[i][2]) | ((uint32)f2bf(acc[i][3]) << 16);
      *(uint2*)(Hb + (size_t)n * 32 + tf / 2) = make_uint2(p0, p1);
    }
  }
}

// Fused: CSR aggregate over bf16 H (wave = node; lane = feature-PAIR; the two
// 32-lane halves process even/odd edges concurrently -> 2 edges per load
// instruction, 128B per edge) + bias + relu, then the NEXT layer's 64x64
// linear via wave-local LDS exchange. FINAL=1: 64->2 linear + log_softmax.
template <int FINAL>
__global__ __launch_bounds__(256) void prop_fused_kernel(
    const uint32* __restrict__ H32, const int* __restrict__ rowptr,
    const int2* __restrict__ col2, const float* __restrict__ dinv,
    const float* __restrict__ bias, const float* __restrict__ Wn,
    const float* __restrict__ blin, void* __restrict__ outv, int N) {
  __shared__ float Ws[64 * 64];
  __shared__ float rbuf[4][64];
  const int lane = threadIdx.x & 63;
  const int widx = threadIdx.x >> 6;
  const int fl = lane & 31;   // feature-pair index (features 2fl, 2fl+1)
  const int half = lane >> 5; // 0: even edges, 1: odd edges

  if (!FINAL) {
    const float4* Wg = (const float4*)Wn;
    float4* Wl = (float4*)Ws;
    for (int i = threadIdx.x; i < 1024; i += 256) Wl[i] = Wg[i];
    __syncthreads();
  }

  int n = blockIdx.x * 4 + widx;
  n = __builtin_amdgcn_readfirstlane(n);
  if (n >= N) return;

  int e0 = rowptr[n];
  int e1 = rowptr[n + 1];
  float di = dinv[n];
  const int2* ec = col2 + e0;
  const int m = e1 - e0;

  float acc0 = 0.f, acc1 = 0.f;
  if (half == 0) {  // self-loop counted once
    uint32 u = H32[(size_t)n * 32 + fl];
    float w = di * di;
    acc0 = bf2f_lo(u) * w;
    acc1 = bf2f_hi(u) * w;
  }

  const int npair = m >> 1;
  const int nfull = npair >> 3;
  for (int b = 0; b < nfull; ++b) {
    int s[8];
    float wv[8];
#pragma unroll
    for (int j = 0; j < 8; ++j) {
      int2 c = ec[2 * (b * 8 + j) + half];
      s[j] = c.x;
      wv[j] = __int_as_float(c.y);
    }
    uint32 u[8];
#pragma unroll
    for (int j = 0; j < 8; ++j) u[j] = H32[(size_t)s[j] * 32 + fl];
#pragma unroll
    for (int j = 0; j < 8; ++j) {
      acc0 = fmaf(wv[j], bf2f_lo(u[j]), acc0);
      acc1 = fmaf(wv[j], bf2f_hi(u[j]), acc1);
    }
  }
  for (int t = nfull * 8; t < npair; ++t) {
    int2 c = ec[2 * t + half];
    uint32 u = H32[(size_t)c.x * 32 + fl];
    float w = __int_as_float(c.y);
    acc0 = fmaf(w, bf2f_lo(u), acc0);
    acc1 = fmaf(w, bf2f_hi(u), acc1);
  }
  if ((m & 1) && half == 0) {  // odd tail edge
    int2 c = ec[m - 1];
    uint32 u = H32[(size_t)c.x * 32 + fl];
    float w = __int_as_float(c.y);
    acc0 = fmaf(w, bf2f_lo(u), acc0);
    acc1 = fmaf(w, bf2f_hi(u), acc1);
  }
  // combine even/odd halves (lane ^ 32 holds the other partial)
  acc0 += __shfl_xor(acc0, 32, 64);
  acc1 += __shfl_xor(acc1, 32, 64);

  float2 bv = ((const float2*)bias)[fl];
  float r0 = acc0 + bv.x;
  float r1 = acc1 + bv.y;
  r0 = r0 > 0.f ? r0 : 0.f;
  r1 = r1 > 0.f ? r1 : 0.f;

  if (FINAL) {
    float t0 = 0.f, t1 = 0.f;
    if (half == 0) {
      t0 = r0 * Wn[4 * fl + 0] + r1 * Wn[4 * fl + 2];
      t1 = r0 * Wn[4 * fl + 1] + r1 * Wn[4 * fl + 3];
    }
#pragma unroll
    for (int off = 32; off > 0; off >>= 1) {
      t0 += __shfl_xor(t0, off, 64);
      t1 += __shfl_xor(t1, off, 64);
    }
    if (lane == 0) {
      float* out = (float*)outv;
      float l0 = t0 + blin[0];
      float l1 = t1 + blin[1];
      float mx = fmaxf(l0, l1);
      float lz = mx + logf(expf(l0 - mx) + expf(l1 - mx));
      out[(size_t)n * 2 + 0] = l0 - lz;
      out[(size_t)n * 2 + 1] = l1 - lz;
    }
  } else {
    if (half == 0) *(float2*)(&rbuf[widx][2 * fl]) = make_float2(r0, r1);
    __builtin_amdgcn_wave_barrier();  // ordering only; compiler inserts waits
    float o = 0.f;
#pragma unroll
    for (int q = 0; q < 16; ++q) {
      float4 rv = *(const float4*)(&rbuf[widx][4 * q]);
      o = fmaf(rv.x, Ws[(4 * q + 0) * 64 + lane], o);
      o = fmaf(rv.y, Ws[(4 * q + 1) * 64 + lane], o);
      o = fmaf(rv.z, Ws[(4 * q + 2) * 64 + lane], o);
      o = fmaf(rv.w, Ws[(4 * q + 3) * 64 + lane], o);
    }
    ((unsigned short*)outv)[(size_t)n * 64 + lane] = f2bf(o);
  }
}

// ---------------- launcher ----------------

extern "C" void kernel_launch(void* const* d_in, const int* in_sizes, int n_in,
                              void* d_out, int out_size, void* d_ws, size_t ws_size,
                              hipStream_t stream) {
  const float* x  = (const float*)d_in[0];
  const int*   ei = (const int*)d_in[1];
  const float* W1 = (const float*)d_in[2];
  const float* b1 = (const float*)d_in[3];
  const float* W2 = (const float*)d_in[4];
  const float* b2 = (const float*)d_in[5];
  const float* W3 = (const float*)d_in[6];
  const float* b3 = (const float*)d_in[7];
  const float* Wl = (const float*)d_in[8];
  const float* bl = (const float*)d_in[9];
  float* out = (float*)d_out;

  const int N = in_sizes[0] / NF;  // 100000
  const int E = in_sizes[1] / 2;   // 1600000

  char* w = (char*)d_ws;
  size_t off = 0;
  auto alloc = [&](size_t bytes) {
    void* p = w + off;
    off += bytes;
    off = (off + 15) & ~(size_t)15;
    return p;
  };
  int*    cnt    = (int*)alloc((size_t)N * 4);
  int*    cnt2   = (int*)alloc((size_t)N * 4);
  int*    rowptr = (int*)alloc((size_t)(N + 1) * 4);
  int*    part   = (int*)alloc(256 * 4);
  float*  dinv   = (float*)alloc((size_t)N * 4);
  int2*   col2   = (int2*)alloc((size_t)E * 8);
  uint32* hA     = (uint32*)alloc((size_t)N * 32 * 4);  // bf16 x2 packed
  uint32* hB     = (uint32*)alloc((size_t)N * 32 * 4);

  const int NB = (N + 1023) / 1024;       // 98 (<=128 required by scanp)
  const int RW = (N + 7) / 8;             // 12500-node dst window per XCD
  const int NCHUNK = (E / 4 + 255) / 256; // edge-quad chunks

  hipMemsetAsync(cnt, 0, (size_t)N * 4, stream);
  hipLaunchKernelGGL(count_kernel, dim3(8 * NCHUNK), dim3(256), 0, stream,
                     ei, E, cnt, RW);
  hipLaunchKernelGGL(partial_kernel, dim3(NB), dim3(256), 0, stream, cnt, N, part);
  hipLaunchKernelGGL(scanp_kernel, dim3(1), dim3(128), 0, stream, part, NB, rowptr + N);
  hipLaunchKernelGGL(rowptr_kernel, dim3(NB), dim3(256), 0, stream,
                     cnt, part, rowptr, cnt2, dinv, N);
  hipLaunchKernelGGL(fill_kernel, dim3(8 * NCHUNK), dim3(256), 0, stream,
                     ei, E, cnt2, dinv, col2, RW);

  hipLaunchKernelGGL(gemm_kernel<128>, dim3((N + 63) / 64), dim3(256), 0, stream,
                     x, W1, hA, N);
  hipLaunchKernelGGL(prop_fused_kernel<0>, dim3((N + 3) / 4), dim3(256), 0, stream,
                     hA, rowptr, col2, dinv, b1, W2, (const float*)nullptr, (void*)hB, N);
  hipLaunchKernelGGL(prop_fused_kernel<0>, dim3((N + 3) / 4), dim3(256), 0, stream,
                     hB, rowptr, col2, dinv, b2, W3, (const float*)nullptr, (void*)hA, N);
  hipLaunchKernelGGL(prop_fused_kernel<1>, dim3((N + 3) / 4), dim3(256), 0, stream,
                     hA, rowptr, col2, dinv, b3, Wl, bl, (void*)out, N);
}